// Round 9
// baseline (395.682 us; speedup 1.0000x reference)
//
#include <hip/hip_runtime.h>
#include <hip/hip_bf16.h>

typedef unsigned short u16;
typedef unsigned int u32;
using floatx4 = __attribute__((ext_vector_type(4))) float;
using short8  = __attribute__((ext_vector_type(8))) short;
using short4v = __attribute__((ext_vector_type(4))) short;
using bf16x8  = __attribute__((ext_vector_type(8))) __bf16;
using u32x4   = __attribute__((ext_vector_type(4))) u32;

#define B_ 4096
#define F_ 40
#define E_ 64
#define H_ 4
#define A_ 64
#define C_ 256

__device__ __forceinline__ float bf2f(u16 h) {
  u32 u = ((u32)h) << 16;
  return __builtin_bit_cast(float, u);
}
__device__ __forceinline__ u16 f2bf(float f) {  // RNE via hardware cvt, finite inputs
  return __builtin_bit_cast(u16, (__bf16)f);
}
__device__ __forceinline__ u32 pkw(float x, float y) {  // bf16 pair word (x = low)
  return (u32)f2bf(x) | ((u32)f2bf(y) << 16);
}
__device__ __forceinline__ floatx4 mfma16(bf16x8 a, bf16x8 b, floatx4 c) {
  return __builtin_amdgcn_mfma_f32_16x16x32_bf16(a, b, c, 0, 0, 0);
}
// Pin a fragment into VGPRs: value becomes an asm output -> NOT rematerializable.
// (R8 lesson: compiler kept VGPR=56 and re-loaded X from global + redid the
// fp32->split conversion at every use site; ~4x VALU inflation.)
__device__ __forceinline__ void keep(bf16x8& x) {
  u32x4 t = __builtin_bit_cast(u32x4, x);
  asm volatile("" : "+v"(t));
  x = __builtin_bit_cast(bf16x8, t);
}

// ---- C-frag -> B-frag in-register redistribution (within 16-lane row groups) ----
__device__ __forceinline__ u32 selshfl(u32 E, u32 F, int src, bool useE) {
  u32 e = (u32)__shfl((int)E, src);
  u32 f = (u32)__shfl((int)F, src);
  return useE ? e : f;
}
__device__ __forceinline__ bf16x8 redist(u32 Ta0, u32 Ta1, u32 Tb0, u32 Tb1,
                                         int q, int r) {
  bool loT = (q < 2);                       // this lane's tile as a SOURCE
  u32 E0 = loT ? Ta0 : Tb0, F0 = loT ? Tb0 : Ta0;
  u32 E1 = loT ? Ta1 : Tb1, F1 = loT ? Tb1 : Ta1;
  bool useE = (q == 0) || (q == 3);         // target-lane tile selector
  int s0 = ((q & 1) * 2) * 16 + r;
  int s1 = s0 + 16;
  u32x4 v;
  v[0] = selshfl(E0, F0, s0, useE);
  v[1] = selshfl(E1, F1, s0, useE);
  v[2] = selshfl(E0, F0, s1, useE);
  v[3] = selshfl(E1, F1, s1, useE);
  return __builtin_bit_cast(bf16x8, v);
}
// half variant: k 0..15 from Tc, k 16..31 = zero (pad)
__device__ __forceinline__ bf16x8 redist_half(u32 Tc0, u32 Tc1, int q, int r) {
  int s0 = ((q & 1) * 2) * 16 + r;
  int s1 = s0 + 16;
  u32x4 v;
  v[0] = (u32)__shfl((int)Tc0, s0);
  v[1] = (u32)__shfl((int)Tc1, s0);
  v[2] = (u32)__shfl((int)Tc0, s1);
  v[3] = (u32)__shfl((int)Tc1, s1);
  if (q >= 2) { v[0] = 0; v[1] = 0; v[2] = 0; v[3] = 0; }
  return __builtin_bit_cast(bf16x8, v);
}

// dtype sniff: bf16 weights have sane exponents in all 64 u16s; fp32 data's
// low halves are random bits (expect ~40/64 sane). Threshold 56 (6.6 sigma).
__device__ __forceinline__ bool detect_bf16(const void* Wq) {
  int lane = threadIdx.x & 63;
  u16 w = ((const u16*)Wq)[lane];
  int e = (w >> 7) & 0xFF;
  bool sane = (e == 0) || (e >= 96 && e <= 159);
  return __popcll(__ballot(sane)) >= 56;
}

// fallback: element gather + hi/lo split straight from source weights
__device__ __forceinline__ void gather2(const void* W, bool bf, int stride, int col,
                                        int kc, int q, bf16x8& hi, bf16x8& lo) {
  short8 h8 = {0, 0, 0, 0, 0, 0, 0, 0}, l8 = {0, 0, 0, 0, 0, 0, 0, 0};
  int e0 = kc * 32 + q * 8;
#pragma unroll
  for (int j = 0; j < 8; ++j) {
    long off = (long)(e0 + j) * stride + col;
    float v = bf ? bf2f(((const u16*)W)[off]) : ((const float*)W)[off];
    u16 hh = f2bf(v);
    h8[j] = (short)hh;
    l8[j] = (short)f2bf(v - bf2f(hh));
  }
  hi = __builtin_bit_cast(bf16x8, h8);
  lo = __builtin_bit_cast(bf16x8, l8);
}

// fallback: on-the-fly M = Wq.Wk^T fragment (head-offset pointers), hi/lo split
__device__ __forceinline__ void gatherM2(const void* Wqh, const void* Wkh, bool bf,
                                         int kc, int q, int col, bf16x8& hi, bf16x8& lo) {
  short8 h8 = {0, 0, 0, 0, 0, 0, 0, 0}, l8 = {0, 0, 0, 0, 0, 0, 0, 0};
  int e0 = kc * 32 + q * 8;
#pragma unroll
  for (int j = 0; j < 8; ++j) {
    int e1 = e0 + j;
    float acc = 0.f;
    for (int a = 0; a < 64; ++a) {
      float wq = bf ? bf2f(((const u16*)Wqh)[e1 * 64 + a]) : ((const float*)Wqh)[e1 * 64 + a];
      float wk = bf ? bf2f(((const u16*)Wkh)[col * 64 + a]) : ((const float*)Wkh)[col * 64 + a];
      acc += wq * wk;
    }
    u16 hh = f2bf(acc);
    h8[j] = (short)hh;
    l8[j] = (short)f2bf(acc - bf2f(hh));
  }
  hi = __builtin_bit_cast(bf16x8, h8);
  lo = __builtin_bit_cast(bf16x8, l8);
}

// Pack weights into MFMA fragment order (symmetric layout usable as A or B).
// ws u16 layout: [MH 16384][ML 16384][VH 16384][ResH 16384]  (65536 u16 = 128 KiB)
// M_h = Wq_h . Wk_h^T  (E x E), computed fp32-exact here, split hi/lo.
// frag(h,t,kc) elem[lane*8+j] = Mat[k = kc*32+(lane>>4)*8+j][col = t*16+(lane&15)]
__global__ void pack_w(const void* __restrict__ Wq, const void* __restrict__ Wk,
                       const void* __restrict__ Wv, const void* __restrict__ Wres,
                       u16* __restrict__ ws) {
  bool bf = detect_bf16(Wq);
  int idx = blockIdx.x * 256 + threadIdx.x;  // 0..49151
  int s = idx >> 14;                         // 0:M, 1:V, 2:Res
  int within = idx & 16383;
  int frag = within >> 9;
  int h = frag >> 3, t = (frag >> 1) & 3, kc = frag & 1;
  int pos = within & 511;
  int lane = pos >> 3, j = pos & 7;
  int q = lane >> 4, r = lane & 15;
  int e = kc * 32 + q * 8 + j;
  int col = t * 16 + r;
  if (s == 0) {
    // M[e][col] = sum_a Wq[h][e][a] * Wk[h][col][a]  (fp32 exact)
    float acc = 0.f;
    if (bf) {
      const u16* wq = (const u16*)Wq + ((long)h * 64 + e) * 64;
      const u16* wk = (const u16*)Wk + ((long)h * 64 + col) * 64;
      for (int a = 0; a < 64; ++a) acc += bf2f(wq[a]) * bf2f(wk[a]);
    } else {
      const float* wq = (const float*)Wq + ((long)h * 64 + e) * 64;
      const float* wk = (const float*)Wk + ((long)h * 64 + col) * 64;
      for (int a = 0; a < 64; ++a) acc += wq[a] * wk[a];
    }
    u16 hi = f2bf(acc);
    ws[idx] = hi;                                // MH
    ws[idx + 16384] = f2bf(acc - bf2f(hi));      // ML
  } else {
    const void* src;
    long off;
    if (s == 1) { src = Wv;   off = ((long)h * 64 + e) * 64 + col; }
    else        { src = Wres; off = (long)e * 256 + h * 64 + col; }
    float v = bf ? bf2f(((const u16*)src)[off]) : ((const float*)src)[off];
    ws[idx + 16384] = f2bf(v);  // s=1 -> [32768,49152) VH ; s=2 -> [49152,65536) ResH
  }
}

// One block = one (batch b, head h). 4 waves, ONE barrier.
// X never touches LDS (R8): each wave loads its 12 X fragments directly from
// global (L2-hot across the block's waves) and splits in registers. R9 change:
// the fragments are PINNED in VGPRs via an opaque asm pass-through, so the
// load+split happens exactly once (R8's VGPR=56 proved the compiler was
// re-loading + re-converting at every use site -> ~4x VALU inflation, 72%
// VALUBusy). Budget: 48 X + ~60 working set < 128 cap (launch_bounds 256,4).
//   T^T = M^T.X^T               (TH/TL packed b64 writes, layout [f][a])
//   V   = X.Wv, stored transposed into VT[a][f] (packed writes)
//   S^T = X.T^T                 (lane holds a full S row; in-register softmax)
//   P in registers (12 bpermute redistribution)
//   O^T = V^T.P^T + Wres^T.X^T  (epilogue = 4 float4 stores)
template <bool USEWS>
__global__ __launch_bounds__(256, 4) void autoint_attn(
    const void* __restrict__ Xv, const void* __restrict__ Wq,
    const void* __restrict__ Wk, const void* __restrict__ Wv,
    const void* __restrict__ Wres, const u16* __restrict__ wp,
    void* __restrict__ outv) {
  __shared__ __align__(16) u16 smem[11520];  // 23040 B
  const int tid = threadIdx.x;
  // XCD-friendly decode: all 4 heads of a batch b map to blockIdx values that are
  // congruent mod 8 and adjacent in dispatch order -> X[b] stays in one XCD's L2.
  const int blk = blockIdx.x;
  const int b = ((blk >> 5) << 3) | (blk & 7);
  const int h = (blk >> 3) & 3;
  const int w = tid >> 6, lane = tid & 63;
  const int q = lane >> 4, r = lane & 15;
  const bool bf = detect_bf16(Wq);

  u16* TH = smem;             // [48 f][72] cols a  3456 u16
  u16* TL = smem + 3456;      // [48 f][72]         3456 u16
  u16* VT = smem + 6912;      // [64 a][72] cols f (48..63 zeroed)  4608 u16

  const u16* PMH = wp;
  const u16* PML = wp + 16384;
  const u16* PVH = wp + 32768;
  const u16* PRH = wp + 49152;

  // ---- issue weight-frag global loads early ----
  bf16x8 mh[2], ml[2], wvf[2];
  if constexpr (USEWS) {
#pragma unroll
    for (int kc = 0; kc < 2; ++kc) {
      mh[kc]  = *(const bf16x8*)(PMH + ((h * 4 + w) * 2 + kc) * 512 + lane * 8);
      ml[kc]  = *(const bf16x8*)(PML + ((h * 4 + w) * 2 + kc) * 512 + lane * 8);
      wvf[kc] = *(const bf16x8*)(PVH + ((h * 4 + w) * 2 + kc) * 512 + lane * 8);
    }
  }

  // ---- X fragments straight from global; split in registers (NO LDS) ----
  // xh[mt][kc] elem j = X[b][mt*16 + r][kc*32 + q*8 + j]; rows 40..47 zero-pad.
  bf16x8 xh[3][2], xl[3][2];
#pragma unroll
  for (int mt = 0; mt < 3; ++mt) {
    const int fr = mt * 16 + r;
    const bool valid = (fr < F_);
#pragma unroll
    for (int kc = 0; kc < 2; ++kc) {
      short8 h8 = {0, 0, 0, 0, 0, 0, 0, 0}, l8 = {0, 0, 0, 0, 0, 0, 0, 0};
      const int e0 = kc * 32 + q * 8;
      if (valid) {
        if (bf) {
          h8 = *(const short8*)((const u16*)Xv + ((size_t)b * F_ + fr) * E_ + e0);
        } else {
          const float* xp = (const float*)Xv + ((size_t)b * F_ + fr) * E_ + e0;
          float4 p0 = *(const float4*)xp;
          float4 p1 = *(const float4*)(xp + 4);
          float vals[8] = {p0.x, p0.y, p0.z, p0.w, p1.x, p1.y, p1.z, p1.w};
#pragma unroll
          for (int j = 0; j < 8; ++j) {
            u16 hh = f2bf(vals[j]);
            h8[j] = (short)hh;
            l8[j] = (short)f2bf(vals[j] - bf2f(hh));
          }
        }
      }
      xh[mt][kc] = __builtin_bit_cast(bf16x8, h8);
      xl[mt][kc] = __builtin_bit_cast(bf16x8, l8);
      keep(xh[mt][kc]);   // pin: load+split exactly once (R9)
      keep(xl[mt][kc]);
    }
  }

  if constexpr (!USEWS) {
    const void* Wq_p = bf ? (const void*)((const u16*)Wq + h * 4096)
                          : (const void*)((const float*)Wq + h * 4096);
    const void* Wk_p = bf ? (const void*)((const u16*)Wk + h * 4096)
                          : (const void*)((const float*)Wk + h * 4096);
    const void* Wv_p = bf ? (const void*)((const u16*)Wv + h * 4096)
                          : (const void*)((const float*)Wv + h * 4096);
    for (int kc = 0; kc < 2; ++kc) {
      gatherM2(Wq_p, Wk_p, bf, kc, q, w * 16 + r, mh[kc], ml[kc]);
      bf16x8 d;
      gather2(Wv_p, bf, 64, w * 16 + r, kc, q, wvf[kc], d);
    }
  }

  // ---- Phase 1: T^T = M^T.X^T, a-tile w; packed split writes into TH/TL ----
  {
#pragma unroll
    for (int mt = 0; mt < 3; ++mt) {
      floatx4 at = {0.f, 0.f, 0.f, 0.f};
#pragma unroll
      for (int kc = 0; kc < 2; ++kc) {
        at = mfma16(mh[kc], xh[mt][kc], at);   // Mh^T . Xh^T
        at = mfma16(ml[kc], xh[mt][kc], at);   // Ml^T . Xh^T
        at = mfma16(mh[kc], xl[mt][kc], at);   // Mh^T . Xl^T
      }
      // lane holds T[f = mt*16+r][a = w*16+q*4+i], i=0..3 consecutive
      short4v hv, lv;
#pragma unroll
      for (int i = 0; i < 4; ++i) {
        u16 hh = f2bf(at[i]);
        hv[i] = (short)hh;
        lv[i] = (short)f2bf(at[i] - bf2f(hh));
      }
      int off = (mt * 16 + r) * 72 + w * 16 + q * 4;
      *(short4v*)(TH + off) = hv;
      *(short4v*)(TL + off) = lv;
    }
  }

  // ---- Phase 1: V = X.Wv (a-tile w), stored transposed into VT[a][f] ----
  {
#pragma unroll
    for (int nt = 0; nt < 3; ++nt) {   // f-tiles
      floatx4 av = {0.f, 0.f, 0.f, 0.f};
      av = mfma16(xh[nt][0], wvf[0], av);
      av = mfma16(xh[nt][1], wvf[1], av);
      // lane holds V[f = nt*16+q*4+i][a = w*16+r]
      short4v vv;
#pragma unroll
      for (int i = 0; i < 4; ++i) vv[i] = (short)f2bf(av[i]);
      *(short4v*)(VT + (w * 16 + r) * 72 + nt * 16 + q * 4) = vv;
    }
    // zero pad cols f=48..63 (vb1's k 48..63 multiply pf1 zeros, but must be
    // finite bf16, not garbage)
    short4v z = {0, 0, 0, 0};
    *(short4v*)(VT + (w * 16 + (lane >> 2)) * 72 + 48 + (lane & 3) * 4) = z;
  }
  __syncthreads();  // the ONLY barrier: T/V visible

  // ---- Phase 2 (3 active waves; role rotates by blockIdx across SIMDs) ----
  const int mtRole = (w + blk) & 3;
  if (mtRole < 3) {
    const int mt = mtRole;
    const int prow = (mt * 16 + r) * 72;
    bf16x8 thf[2], tlf[2];
#pragma unroll
    for (int kc = 0; kc < 2; ++kc) {
      thf[kc] = *(const bf16x8*)(TH + prow + kc * 32 + q * 8);
      tlf[kc] = *(const bf16x8*)(TL + prow + kc * 32 + q * 8);
    }

    // S^T tiles: lane holds S[f = mt*16+r][g = gt*16+q*4+i]  (full row per lane)
    floatx4 sg[3];
#pragma unroll
    for (int gt = 0; gt < 3; ++gt) {
      floatx4 s = {0.f, 0.f, 0.f, 0.f};
#pragma unroll
      for (int kc = 0; kc < 2; ++kc) {
        s = mfma16(xh[gt][kc], thf[kc], s);   // Xh . Th^T
        s = mfma16(xl[gt][kc], thf[kc], s);   // Xl . Th^T
        s = mfma16(xh[gt][kc], tlf[kc], s);   // Xh . Tl^T
      }
      sg[gt] = s;
    }
    // in-register softmax over g; gt=2 has g=32+q*4+i, valid iff q<2
    const bool ok2 = (q < 2);
    float m = fmaxf(fmaxf(sg[0][0], sg[0][1]), fmaxf(sg[0][2], sg[0][3]));
    m = fmaxf(m, fmaxf(fmaxf(sg[1][0], sg[1][1]), fmaxf(sg[1][2], sg[1][3])));
    if (ok2)
      m = fmaxf(m, fmaxf(fmaxf(sg[2][0], sg[2][1]), fmaxf(sg[2][2], sg[2][3])));
    m = fmaxf(m, __shfl_xor(m, 16, 64));
    m = fmaxf(m, __shfl_xor(m, 32, 64));
    float p0[4], p1[4], p2[4], sum = 0.f;
#pragma unroll
    for (int i = 0; i < 4; ++i) {
      p0[i] = __expf(sg[0][i] - m);
      p1[i] = __expf(sg[1][i] - m);
      p2[i] = ok2 ? __expf(sg[2][i] - m) : 0.f;
      sum += p0[i] + p1[i] + p2[i];
    }
    sum += __shfl_xor(sum, 16, 64);
    sum += __shfl_xor(sum, 32, 64);
    float inv = 1.f / sum;

    // Wres prefetch HERE (sg dead, P-shuffle latency below covers the L2 hit)
    bf16x8 wr0[4], wr1[4];
    if constexpr (USEWS) {
#pragma unroll
      for (int nt = 0; nt < 4; ++nt) {
        wr0[nt] = *(const bf16x8*)(PRH + ((h * 4 + nt) * 2 + 0) * 512 + lane * 8);
        wr1[nt] = *(const bf16x8*)(PRH + ((h * 4 + nt) * 2 + 1) * 512 + lane * 8);
      }
    } else {
      for (int nt = 0; nt < 4; ++nt) {
        bf16x8 d;
        gather2(Wres, bf, 256, h * 64 + nt * 16 + r, 0, q, wr0[nt], d);
        gather2(Wres, bf, 256, h * 64 + nt * 16 + r, 1, q, wr1[nt], d);
      }
    }

    // P entirely in registers: pack normalized bf16 pairs, then build the PV
    // A-fragments by in-wave redistribution (no LDS round-trip).
    u32 A0 = pkw(p0[0] * inv, p0[1] * inv);
    u32 A1 = pkw(p0[2] * inv, p0[3] * inv);
    u32 B0 = pkw(p1[0] * inv, p1[1] * inv);
    u32 B1 = pkw(p1[2] * inv, p1[3] * inv);
    u32 C0 = pkw(p2[0] * inv, p2[1] * inv);   // zeros where ok2 false
    u32 C1 = pkw(p2[2] * inv, p2[3] * inv);
    bf16x8 pf0 = redist(A0, A1, B0, B1, q, r);        // g 0..31
    bf16x8 pf1 = redist_half(C0, C1, q, r);           // g 32..47, 48..63 = 0

    // O^T = V^T.P^T + Wres^T.X^T, relu, packed store
#pragma unroll
    for (int nt = 0; nt < 4; ++nt) {
      floatx4 acc = {0.f, 0.f, 0.f, 0.f};
      acc = mfma16(wr0[nt], xh[mt][0], acc);
      acc = mfma16(wr1[nt], xh[mt][1], acc);
      bf16x8 vb0 = *(const bf16x8*)(VT + (nt * 16 + r) * 72 + q * 8);
      bf16x8 vb1 = *(const bf16x8*)(VT + (nt * 16 + r) * 72 + 32 + q * 8);
      acc = mfma16(vb0, pf0, acc);
      acc = mfma16(vb1, pf1, acc);
      // lane holds O[f = mt*16+r][c = h*64 + nt*16 + q*4+i], i consecutive
      int f = mt * 16 + r;
      if (f < F_) {
        size_t o = ((size_t)b * F_ + f) * C_ + h * 64 + nt * 16 + q * 4;
        if (bf) {
          short4v ov;
#pragma unroll
          for (int i = 0; i < 4; ++i) ov[i] = (short)f2bf(fmaxf(acc[i], 0.f));
          *(short4v*)((u16*)outv + o) = ov;
        } else {
          floatx4 ov;
#pragma unroll
          for (int i = 0; i < 4; ++i) ov[i] = fmaxf(acc[i], 0.f);
          *(floatx4*)((float*)outv + o) = ov;
        }
      }
    }
  }
}

extern "C" void kernel_launch(void* const* d_in, const int* in_sizes, int n_in,
                              void* d_out, int out_size, void* d_ws, size_t ws_size,
                              hipStream_t stream) {
  (void)in_sizes; (void)n_in; (void)out_size;
  const void* X    = d_in[0];
  const void* Wq   = d_in[1];
  const void* Wk   = d_in[2];
  const void* Wv   = d_in[3];
  const void* Wres = d_in[4];

  bool usews = (d_ws != nullptr) && (ws_size >= 131072);
  if (usews) {
    pack_w<<<192, 256, 0, stream>>>(Wq, Wk, Wv, Wres, (u16*)d_ws);
    autoint_attn<true><<<B_ * H_, 256, 0, stream>>>(X, Wq, Wk, Wv, Wres,
                                                    (const u16*)d_ws, d_out);
  } else {
    autoint_attn<false><<<B_ * H_, 256, 0, stream>>>(X, Wq, Wk, Wv, Wres,
                                                     nullptr, d_out);
  }
}

// Round 10
// 368.224 us; speedup vs baseline: 1.0746x; 1.0746x over previous
//
#include <hip/hip_runtime.h>
#include <hip/hip_bf16.h>

typedef unsigned short u16;
typedef unsigned int u32;
using floatx4 = __attribute__((ext_vector_type(4))) float;
using short8  = __attribute__((ext_vector_type(8))) short;
using short4v = __attribute__((ext_vector_type(4))) short;
using bf16x8  = __attribute__((ext_vector_type(8))) __bf16;

#define B_ 4096
#define F_ 40
#define E_ 64
#define H_ 4
#define A_ 64
#define C_ 256

__device__ __forceinline__ float bf2f(u16 h) {
  u32 u = ((u32)h) << 16;
  return __builtin_bit_cast(float, u);
}
__device__ __forceinline__ u16 f2bf(float f) {  // RNE via hardware cvt, finite inputs
  return __builtin_bit_cast(u16, (__bf16)f);
}
__device__ __forceinline__ floatx4 mfma16(bf16x8 a, bf16x8 b, floatx4 c) {
  return __builtin_amdgcn_mfma_f32_16x16x32_bf16(a, b, c, 0, 0, 0);
}

// dtype sniff: bf16 weights have sane exponents in all 64 u16s; fp32 data's
// low halves are random bits (expect ~40/64 sane). Threshold 56 (6.6 sigma).
__device__ __forceinline__ bool detect_bf16(const void* Wq) {
  int lane = threadIdx.x & 63;
  u16 w = ((const u16*)Wq)[lane];
  int e = (w >> 7) & 0xFF;
  bool sane = (e == 0) || (e >= 96 && e <= 159);
  return __popcll(__ballot(sane)) >= 56;
}

// fallback: element gather + hi/lo split straight from source weights
__device__ __forceinline__ void gather2(const void* W, bool bf, int stride, int col,
                                        int kc, int q, bf16x8& hi, bf16x8& lo) {
  short8 h8 = {0, 0, 0, 0, 0, 0, 0, 0}, l8 = {0, 0, 0, 0, 0, 0, 0, 0};
  int e0 = kc * 32 + q * 8;
#pragma unroll
  for (int j = 0; j < 8; ++j) {
    long off = (long)(e0 + j) * stride + col;
    float v = bf ? bf2f(((const u16*)W)[off]) : ((const float*)W)[off];
    u16 hh = f2bf(v);
    h8[j] = (short)hh;
    l8[j] = (short)f2bf(v - bf2f(hh));
  }
  hi = __builtin_bit_cast(bf16x8, h8);
  lo = __builtin_bit_cast(bf16x8, l8);
}

// fallback: on-the-fly M = Wq.Wk^T fragment (head-offset pointers), hi/lo split
__device__ __forceinline__ void gatherM2(const void* Wqh, const void* Wkh, bool bf,
                                         int kc, int q, int col, bf16x8& hi, bf16x8& lo) {
  short8 h8 = {0, 0, 0, 0, 0, 0, 0, 0}, l8 = {0, 0, 0, 0, 0, 0, 0, 0};
  int e0 = kc * 32 + q * 8;
#pragma unroll
  for (int j = 0; j < 8; ++j) {
    int e1 = e0 + j;
    float acc = 0.f;
    for (int a = 0; a < 64; ++a) {
      float wq = bf ? bf2f(((const u16*)Wqh)[e1 * 64 + a]) : ((const float*)Wqh)[e1 * 64 + a];
      float wk = bf ? bf2f(((const u16*)Wkh)[col * 64 + a]) : ((const float*)Wkh)[col * 64 + a];
      acc += wq * wk;
    }
    u16 hh = f2bf(acc);
    h8[j] = (short)hh;
    l8[j] = (short)f2bf(acc - bf2f(hh));
  }
  hi = __builtin_bit_cast(bf16x8, h8);
  lo = __builtin_bit_cast(bf16x8, l8);
}

// Pack weights into MFMA fragment order (symmetric layout usable as A or B).
// ws u16 layout: [MH 16384][ML 16384][VH 16384][ResH 16384]  (65536 u16 = 128 KiB)
// M_h = Wq_h . Wk_h^T  (E x E), computed fp32-exact here, split hi/lo.
// frag(h,t,kc) elem[lane*8+j] = Mat[k = kc*32+(lane>>4)*8+j][col = t*16+(lane&15)]
__global__ void pack_w(const void* __restrict__ Wq, const void* __restrict__ Wk,
                       const void* __restrict__ Wv, const void* __restrict__ Wres,
                       u16* __restrict__ ws) {
  bool bf = detect_bf16(Wq);
  int idx = blockIdx.x * 256 + threadIdx.x;  // 0..49151
  int s = idx >> 14;                         // 0:M, 1:V, 2:Res
  int within = idx & 16383;
  int frag = within >> 9;
  int h = frag >> 3, t = (frag >> 1) & 3, kc = frag & 1;
  int pos = within & 511;
  int lane = pos >> 3, j = pos & 7;
  int q = lane >> 4, r = lane & 15;
  int e = kc * 32 + q * 8 + j;
  int col = t * 16 + r;
  if (s == 0) {
    // M[e][col] = sum_a Wq[h][e][a] * Wk[h][col][a]  (fp32 exact)
    float acc = 0.f;
    if (bf) {
      const u16* wq = (const u16*)Wq + ((long)h * 64 + e) * 64;
      const u16* wk = (const u16*)Wk + ((long)h * 64 + col) * 64;
      for (int a = 0; a < 64; ++a) acc += bf2f(wq[a]) * bf2f(wk[a]);
    } else {
      const float* wq = (const float*)Wq + ((long)h * 64 + e) * 64;
      const float* wk = (const float*)Wk + ((long)h * 64 + col) * 64;
      for (int a = 0; a < 64; ++a) acc += wq[a] * wk[a];
    }
    u16 hi = f2bf(acc);
    ws[idx] = hi;                                // MH
    ws[idx + 16384] = f2bf(acc - bf2f(hi));      // ML
  } else {
    const void* src;
    long off;
    if (s == 1) { src = Wv;   off = ((long)h * 64 + e) * 64 + col; }
    else        { src = Wres; off = (long)e * 256 + h * 64 + col; }
    float v = bf ? bf2f(((const u16*)src)[off]) : ((const float*)src)[off];
    ws[idx + 16384] = f2bf(v);  // s=1 -> [32768,49152) VH ; s=2 -> [49152,65536) ResH
  }
}

// One block = one batch b, looping over all 4 heads. 4 waves.
// X is staged+split ONCE per batch; the X staging region is NOT overlaid
// (round-4 lesson) so remat-from-LDS stays possible.
// R10 change (single variable vs R6): occupancy attributes. R6's allocator
// VOLUNTARILY clamped to 64 VGPR (its default 8-waves/EU target) and spilled
// the xh/xl live range to scratch -> ~256 MB phantom HBM traffic (FETCH 88 MB,
// WRITE 360 MB). amdgpu_waves_per_eu(3,3) declares the measured occupancy
// (12 waves/CU, every round) as the target -> VGPR budget ~170, h-loop peak
// pressure ~130 fits, no spill, X converted exactly once per batch.
// Phase-2 roles rotate per head: pr = (w+h)&3, pr==3 idles.
// All MFMAs in transposed form: lane's C-fragment = 4 consecutive columns of
// one row -> packed b64/b128 stores, in-register softmax (2 shfl).
//   T^T = M^T.X^T               (TH/TL packed writes, layout [f][a])
//   V   = X.Wv, stored transposed into VT[a][f] (packed writes)
//   S^T = X.T^T                 (lane holds a full S row)
//   O^T = V^T.P^T + Wres^T.X^T  (epilogue = 4 float4 stores)
template <bool USEWS>
__attribute__((amdgpu_waves_per_eu(3, 3)))
__global__ __launch_bounds__(256) void autoint_attn(
    const void* __restrict__ Xv, const void* __restrict__ Wq,
    const void* __restrict__ Wk, const void* __restrict__ Wv,
    const void* __restrict__ Wres, const u16* __restrict__ wp,
    void* __restrict__ outv) {
  __shared__ __align__(16) u16 smem[17664];  // 35328 B
  const int tid = threadIdx.x;
  const int b = blockIdx.x;                  // 4096 blocks, one batch each
  const int w = tid >> 6, lane = tid & 63;
  const int q = lane >> 4, r = lane & 15;
  const bool bf = detect_bf16(Wq);

  u16* XH = smem;             // [3 mt][2 kc][64 lane][8]  3072 u16 (valid whole kernel)
  u16* XL = smem + 3072;      // 3072 (valid whole kernel)
  u16* TH = smem + 6144;      // [48 f][72] cols a  3456 u16
  u16* TL = smem + 9600;      // [48 f][72]  (aliased by P in phase 2)
  u16* VT = smem + 13056;     // [64 a][72] cols f (48..63 zeroed once)  4608 u16

  const u16* PMH = wp;
  const u16* PML = wp + 16384;
  const u16* PVH = wp + 32768;
  const u16* PRH = wp + 49152;

  // ---- stage X into split A-frag layout (pad rows 40..47 = 0), once per batch ----
  for (int c = tid; c < 384; c += 256) {
    short8 hi8 = {0, 0, 0, 0, 0, 0, 0, 0}, lo8 = {0, 0, 0, 0, 0, 0, 0, 0};
    int f, ec;
    if (c < 320) {
      f = c >> 3; ec = c & 7;
      if (bf) {
        hi8 = *(const short8*)((const u16*)Xv + ((size_t)b * F_ + f) * E_ + ec * 8);
      } else {
        const float* xp = (const float*)Xv + ((size_t)b * F_ + f) * E_ + ec * 8;
        float4 p0 = *(const float4*)xp;
        float4 p1 = *(const float4*)(xp + 4);
        float vals[8] = {p0.x, p0.y, p0.z, p0.w, p1.x, p1.y, p1.z, p1.w};
#pragma unroll
        for (int j = 0; j < 8; ++j) {
          u16 hh = f2bf(vals[j]);
          hi8[j] = (short)hh;
          lo8[j] = (short)f2bf(vals[j] - bf2f(hh));
        }
      }
    } else {
      f = 40 + ((c - 320) >> 3); ec = c & 7;
    }
    int mt = f >> 4, rr = f & 15, kc = ec >> 2, qq = ec & 3;
    int base = ((mt * 2 + kc) * 64 + qq * 16 + rr) * 8;
    *(short8*)(XH + base) = hi8;
    *(short8*)(XL + base) = lo8;
  }
  // zero VT pad cols f=48..63 once per batch (never overwritten by any head;
  // they multiply P's pad region in every head's PV -> must be exactly 0)
  {
    short4v z = {0, 0, 0, 0};
    *(short4v*)(VT + (tid >> 2) * 72 + 48 + (tid & 3) * 4) = z;
  }
  __syncthreads();  // b1: staging + VT pad visible

  bf16x8 xh[3][2], xl[3][2];
#pragma unroll
  for (int mt = 0; mt < 3; ++mt)
#pragma unroll
    for (int kc = 0; kc < 2; ++kc) {
      xh[mt][kc] = *(const bf16x8*)(XH + ((mt * 2 + kc) * 64 + lane) * 8);
      xl[mt][kc] = *(const bf16x8*)(XL + ((mt * 2 + kc) * 64 + lane) * 8);
    }

  for (int h = 0; h < 4; ++h) {
    // ---- weight frags for this head (die before phase 2 -> low pressure) ----
    bf16x8 mh[2], ml[2], wvf[2];
    if constexpr (USEWS) {
#pragma unroll
      for (int kc = 0; kc < 2; ++kc) {
        mh[kc]  = *(const bf16x8*)(PMH + ((h * 4 + w) * 2 + kc) * 512 + lane * 8);
        ml[kc]  = *(const bf16x8*)(PML + ((h * 4 + w) * 2 + kc) * 512 + lane * 8);
        wvf[kc] = *(const bf16x8*)(PVH + ((h * 4 + w) * 2 + kc) * 512 + lane * 8);
      }
    } else {
      const void* Wq_p = bf ? (const void*)((const u16*)Wq + h * 4096)
                            : (const void*)((const float*)Wq + h * 4096);
      const void* Wk_p = bf ? (const void*)((const u16*)Wk + h * 4096)
                            : (const void*)((const float*)Wk + h * 4096);
      const void* Wv_p = bf ? (const void*)((const u16*)Wv + h * 4096)
                            : (const void*)((const float*)Wv + h * 4096);
      for (int kc = 0; kc < 2; ++kc) {
        gatherM2(Wq_p, Wk_p, bf, kc, q, w * 16 + r, mh[kc], ml[kc]);
        bf16x8 d;
        gather2(Wv_p, bf, 64, w * 16 + r, kc, q, wvf[kc], d);
      }
    }
    const int pr = (w + h) & 3;  // phase-2 role (3 = idle), rotates per head

    // ---- Phase 1: T^T = M^T.X^T, a-tile w; packed split writes into TH/TL ----
#pragma unroll
    for (int mt = 0; mt < 3; ++mt) {
      floatx4 at = {0.f, 0.f, 0.f, 0.f};
#pragma unroll
      for (int kc = 0; kc < 2; ++kc) {
        at = mfma16(mh[kc], xh[mt][kc], at);   // Mh^T . Xh^T
        at = mfma16(ml[kc], xh[mt][kc], at);   // Ml^T . Xh^T
        at = mfma16(mh[kc], xl[mt][kc], at);   // Mh^T . Xl^T
      }
      // lane holds T[f = mt*16+r][a = w*16+q*4+i], i=0..3 consecutive
      short4v hv, lv;
#pragma unroll
      for (int i = 0; i < 4; ++i) {
        u16 hh = f2bf(at[i]);
        hv[i] = (short)hh;
        lv[i] = (short)f2bf(at[i] - bf2f(hh));
      }
      int off = (mt * 16 + r) * 72 + w * 16 + q * 4;
      *(short4v*)(TH + off) = hv;
      *(short4v*)(TL + off) = lv;
    }

    // ---- Phase 1: V = X.Wv (a-tile w), stored transposed into VT[a][f] ----
#pragma unroll
    for (int nt = 0; nt < 3; ++nt) {   // f-tiles
      floatx4 av = {0.f, 0.f, 0.f, 0.f};
      av = mfma16(xh[nt][0], wvf[0], av);
      av = mfma16(xh[nt][1], wvf[1], av);
      // lane holds V[f = nt*16+q*4+i][a = w*16+r]
      short4v vv;
#pragma unroll
      for (int i = 0; i < 4; ++i) vv[i] = (short)f2bf(av[i]);
      *(short4v*)(VT + (w * 16 + r) * 72 + nt * 16 + q * 4) = vv;
    }
    __syncthreads();  // b2: T/V of head h visible

    // ---- Phase 2 (waves with pr<3, no barrier inside) ----
    if (pr < 3) {
      const int mt = pr;
      const int prow = (mt * 16 + r) * 72;
      bf16x8 thf[2], tlf[2];
#pragma unroll
      for (int kc = 0; kc < 2; ++kc) {
        thf[kc] = *(const bf16x8*)(TH + prow + kc * 32 + q * 8);
        tlf[kc] = *(const bf16x8*)(TL + prow + kc * 32 + q * 8);
      }
      // S^T tiles: lane holds S[f = mt*16+r][g = gt*16+q*4+i]
      floatx4 sg[3];
#pragma unroll
      for (int gt = 0; gt < 3; ++gt) {
        floatx4 s = {0.f, 0.f, 0.f, 0.f};
#pragma unroll
        for (int kc = 0; kc < 2; ++kc) {
          s = mfma16(xh[gt][kc], thf[kc], s);   // Xh . Th^T
          s = mfma16(xl[gt][kc], thf[kc], s);   // Xl . Th^T
          s = mfma16(xh[gt][kc], tlf[kc], s);   // Xh . Tl^T
        }
        sg[gt] = s;
      }
      // in-register softmax over g; gt=2 has g=32+q*4+i, valid iff q<2
      const bool ok2 = (q < 2);
      float m = fmaxf(fmaxf(sg[0][0], sg[0][1]), fmaxf(sg[0][2], sg[0][3]));
      m = fmaxf(m, fmaxf(fmaxf(sg[1][0], sg[1][1]), fmaxf(sg[1][2], sg[1][3])));
      if (ok2)
        m = fmaxf(m, fmaxf(fmaxf(sg[2][0], sg[2][1]), fmaxf(sg[2][2], sg[2][3])));
      m = fmaxf(m, __shfl_xor(m, 16, 64));
      m = fmaxf(m, __shfl_xor(m, 32, 64));
      float p0[4], p1[4], p2[4], sum = 0.f;
#pragma unroll
      for (int i = 0; i < 4; ++i) {
        p0[i] = __expf(sg[0][i] - m);
        p1[i] = __expf(sg[1][i] - m);
        p2[i] = ok2 ? __expf(sg[2][i] - m) : 0.f;
        sum += p0[i] + p1[i] + p2[i];
      }
      sum += __shfl_xor(sum, 16, 64);
      sum += __shfl_xor(sum, 32, 64);
      float inv = 1.f / sum;
      // P aliases TL (own rows only; tlf already consumed). Cols 40..47 get
      // exact zeros from q>=2 lanes; cols 48..63 keep stale-but-finite TL
      // lo-parts which multiply the zeroed VT pad -> contribute exactly 0.
      u16* P = TL;
      short4v pk;
#pragma unroll
      for (int i = 0; i < 4; ++i) pk[i] = (short)f2bf(p0[i] * inv);
      *(short4v*)(P + prow + q * 4) = pk;
#pragma unroll
      for (int i = 0; i < 4; ++i) pk[i] = (short)f2bf(p1[i] * inv);
      *(short4v*)(P + prow + 16 + q * 4) = pk;
#pragma unroll
      for (int i = 0; i < 4; ++i) pk[i] = (short)f2bf(p2[i] * inv);
      *(short4v*)(P + prow + 32 + q * 4) = pk;

      // Wres frags (inside phase 2, overlapping the drain; die at end of head)
      bf16x8 wr0[4], wr1[4];
      if constexpr (USEWS) {
#pragma unroll
        for (int nt = 0; nt < 4; ++nt) {
          wr0[nt] = *(const bf16x8*)(PRH + ((h * 4 + nt) * 2 + 0) * 512 + lane * 8);
          wr1[nt] = *(const bf16x8*)(PRH + ((h * 4 + nt) * 2 + 1) * 512 + lane * 8);
        }
      } else {
        for (int nt = 0; nt < 4; ++nt) {
          bf16x8 d;
          gather2(Wres, bf, 256, h * 64 + nt * 16 + r, 0, q, wr0[nt], d);
          gather2(Wres, bf, 256, h * 64 + nt * 16 + r, 1, q, wr1[nt], d);
        }
      }

      // same-wave cross-lane LDS RAW: drain ds_writes before reading P frags
      __asm__ __volatile__("s_waitcnt lgkmcnt(0)" ::: "memory");
      bf16x8 pf0 = *(const bf16x8*)(P + prow + q * 8);
      bf16x8 pf1 = *(const bf16x8*)(P + prow + 32 + q * 8);

      // O^T = V^T.P^T + Wres^T.X^T, relu, packed store
#pragma unroll
      for (int nt = 0; nt < 4; ++nt) {
        floatx4 acc = {0.f, 0.f, 0.f, 0.f};
        acc = mfma16(wr0[nt], xh[mt][0], acc);
        acc = mfma16(wr1[nt], xh[mt][1], acc);
        bf16x8 vb0 = *(const bf16x8*)(VT + (nt * 16 + r) * 72 + q * 8);
        bf16x8 vb1 = *(const bf16x8*)(VT + (nt * 16 + r) * 72 + 32 + q * 8);
        acc = mfma16(vb0, pf0, acc);
        acc = mfma16(vb1, pf1, acc);
        // lane holds O[f = mt*16+r][c = h*64 + nt*16 + q*4+i], i consecutive
        int f = mt * 16 + r;
        if (f < F_) {
          size_t o = ((size_t)b * F_ + f) * C_ + h * 64 + nt * 16 + q * 4;
          if (bf) {
            short4v ov;
#pragma unroll
            for (int i = 0; i < 4; ++i) ov[i] = (short)f2bf(fmaxf(acc[i], 0.f));
            *(short4v*)((u16*)outv + o) = ov;
          } else {
            floatx4 ov;
#pragma unroll
            for (int i = 0; i < 4; ++i) ov[i] = fmaxf(acc[i], 0.f);
            *(floatx4*)((float*)outv + o) = ov;
          }
        }
      }
    }
    if (h < 3) __syncthreads();  // b3: phase-2 readers done before next head's T/V
  }
}

extern "C" void kernel_launch(void* const* d_in, const int* in_sizes, int n_in,
                              void* d_out, int out_size, void* d_ws, size_t ws_size,
                              hipStream_t stream) {
  (void)in_sizes; (void)n_in; (void)out_size;
  const void* X    = d_in[0];
  const void* Wq   = d_in[1];
  const void* Wk   = d_in[2];
  const void* Wv   = d_in[3];
  const void* Wres = d_in[4];

  bool usews = (d_ws != nullptr) && (ws_size >= 131072);
  if (usews) {
    pack_w<<<192, 256, 0, stream>>>(Wq, Wk, Wv, Wres, (u16*)d_ws);
    autoint_attn<true><<<B_, 256, 0, stream>>>(X, Wq, Wk, Wv, Wres,
                                               (const u16*)d_ws, d_out);
  } else {
    autoint_attn<false><<<B_, 256, 0, stream>>>(X, Wq, Wk, Wv, Wres,
                                                nullptr, d_out);
  }
}

// Round 11
// 273.819 us; speedup vs baseline: 1.4450x; 1.3448x over previous
//
#include <hip/hip_runtime.h>
#include <hip/hip_bf16.h>

typedef unsigned short u16;
typedef unsigned int u32;
using floatx4 = __attribute__((ext_vector_type(4))) float;
using short8  = __attribute__((ext_vector_type(8))) short;
using short4v = __attribute__((ext_vector_type(4))) short;
using bf16x8  = __attribute__((ext_vector_type(8))) __bf16;
using u32x4   = __attribute__((ext_vector_type(4))) u32;

#define B_ 4096
#define F_ 40
#define E_ 64
#define H_ 4
#define A_ 64
#define C_ 256

__device__ __forceinline__ float bf2f(u16 h) {
  u32 u = ((u32)h) << 16;
  return __builtin_bit_cast(float, u);
}
__device__ __forceinline__ u16 f2bf(float f) {  // RNE via hardware cvt, finite inputs
  return __builtin_bit_cast(u16, (__bf16)f);
}
__device__ __forceinline__ u32 pkw(float x, float y) {  // bf16 pair word (x = low)
  return (u32)f2bf(x) | ((u32)f2bf(y) << 16);
}
__device__ __forceinline__ floatx4 mfma16(bf16x8 a, bf16x8 b, floatx4 c) {
  return __builtin_amdgcn_mfma_f32_16x16x32_bf16(a, b, c, 0, 0, 0);
}

// ---- C-frag -> operand-frag in-register redistribution (R7, bit-exact proven) ----
// Target word W of lane(q,r) = tile (q<2 ? Ta : Tb), source lane (q&1)*2+(W>>1)
// within the same 16-lane row group, source word W&1. Gives operand elem
// j = Mat[row r group][local = q*8+j] from packed C-frag pairs (qs*4+2w,+1).
__device__ __forceinline__ u32 selshfl(u32 E, u32 F, int src, bool useE) {
  u32 e = (u32)__shfl((int)E, src);
  u32 f = (u32)__shfl((int)F, src);
  return useE ? e : f;
}
__device__ __forceinline__ bf16x8 redist(u32 Ta0, u32 Ta1, u32 Tb0, u32 Tb1,
                                         int q, int r) {
  bool loT = (q < 2);                       // this lane's tile as a SOURCE
  u32 E0 = loT ? Ta0 : Tb0, F0 = loT ? Tb0 : Ta0;
  u32 E1 = loT ? Ta1 : Tb1, F1 = loT ? Tb1 : Ta1;
  bool useE = (q == 0) || (q == 3);         // target-lane tile selector
  int s0 = ((q & 1) * 2) * 16 + r;
  int s1 = s0 + 16;
  u32x4 v;
  v[0] = selshfl(E0, F0, s0, useE);
  v[1] = selshfl(E1, F1, s0, useE);
  v[2] = selshfl(E0, F0, s1, useE);
  v[3] = selshfl(E1, F1, s1, useE);
  return __builtin_bit_cast(bf16x8, v);
}
// half variant: local 0..15 from Tc, 16..31 = zero (pad)
__device__ __forceinline__ bf16x8 redist_half(u32 Tc0, u32 Tc1, int q, int r) {
  int s0 = ((q & 1) * 2) * 16 + r;
  int s1 = s0 + 16;
  u32x4 v;
  v[0] = (u32)__shfl((int)Tc0, s0);
  v[1] = (u32)__shfl((int)Tc1, s0);
  v[2] = (u32)__shfl((int)Tc0, s1);
  v[3] = (u32)__shfl((int)Tc1, s1);
  if (q >= 2) { v[0] = 0; v[1] = 0; v[2] = 0; v[3] = 0; }
  return __builtin_bit_cast(bf16x8, v);
}

// dtype sniff: bf16 weights have sane exponents in all 64 u16s; fp32 data's
// low halves are random bits (expect ~40/64 sane). Threshold 56 (6.6 sigma).
__device__ __forceinline__ bool detect_bf16(const void* Wq) {
  int lane = threadIdx.x & 63;
  u16 w = ((const u16*)Wq)[lane];
  int e = (w >> 7) & 0xFF;
  bool sane = (e == 0) || (e >= 96 && e <= 159);
  return __popcll(__ballot(sane)) >= 56;
}

// fallback: element gather + hi/lo split straight from source weights
__device__ __forceinline__ void gather2(const void* W, bool bf, int stride, int col,
                                        int kc, int q, bf16x8& hi, bf16x8& lo) {
  short8 h8 = {0, 0, 0, 0, 0, 0, 0, 0}, l8 = {0, 0, 0, 0, 0, 0, 0, 0};
  int e0 = kc * 32 + q * 8;
#pragma unroll
  for (int j = 0; j < 8; ++j) {
    long off = (long)(e0 + j) * stride + col;
    float v = bf ? bf2f(((const u16*)W)[off]) : ((const float*)W)[off];
    u16 hh = f2bf(v);
    h8[j] = (short)hh;
    l8[j] = (short)f2bf(v - bf2f(hh));
  }
  hi = __builtin_bit_cast(bf16x8, h8);
  lo = __builtin_bit_cast(bf16x8, l8);
}

// fallback: on-the-fly M = Wq.Wk^T fragment (head-offset pointers), hi/lo split
__device__ __forceinline__ void gatherM2(const void* Wqh, const void* Wkh, bool bf,
                                         int kc, int q, int col, bf16x8& hi, bf16x8& lo) {
  short8 h8 = {0, 0, 0, 0, 0, 0, 0, 0}, l8 = {0, 0, 0, 0, 0, 0, 0, 0};
  int e0 = kc * 32 + q * 8;
#pragma unroll
  for (int j = 0; j < 8; ++j) {
    int e1 = e0 + j;
    float acc = 0.f;
    for (int a = 0; a < 64; ++a) {
      float wq = bf ? bf2f(((const u16*)Wqh)[e1 * 64 + a]) : ((const float*)Wqh)[e1 * 64 + a];
      float wk = bf ? bf2f(((const u16*)Wkh)[col * 64 + a]) : ((const float*)Wkh)[col * 64 + a];
      acc += wq * wk;
    }
    u16 hh = f2bf(acc);
    h8[j] = (short)hh;
    l8[j] = (short)f2bf(acc - bf2f(hh));
  }
  hi = __builtin_bit_cast(bf16x8, h8);
  lo = __builtin_bit_cast(bf16x8, l8);
}

// Pack weights into MFMA fragment order (symmetric layout usable as A or B).
// ws u16 layout: [MH 16384][ML 16384][VH 16384][ResH 16384]  (65536 u16 = 128 KiB)
// M_h = Wq_h . Wk_h^T  (E x E), computed fp32-exact here, split hi/lo.
// frag(h,t,kc) elem[lane*8+j] = Mat[k = kc*32+(lane>>4)*8+j][col = t*16+(lane&15)]
__global__ void pack_w(const void* __restrict__ Wq, const void* __restrict__ Wk,
                       const void* __restrict__ Wv, const void* __restrict__ Wres,
                       u16* __restrict__ ws) {
  bool bf = detect_bf16(Wq);
  int idx = blockIdx.x * 256 + threadIdx.x;  // 0..49151
  int s = idx >> 14;                         // 0:M, 1:V, 2:Res
  int within = idx & 16383;
  int frag = within >> 9;
  int h = frag >> 3, t = (frag >> 1) & 3, kc = frag & 1;
  int pos = within & 511;
  int lane = pos >> 3, j = pos & 7;
  int q = lane >> 4, r = lane & 15;
  int e = kc * 32 + q * 8 + j;
  int col = t * 16 + r;
  if (s == 0) {
    // M[e][col] = sum_a Wq[h][e][a] * Wk[h][col][a]  (fp32 exact)
    float acc = 0.f;
    if (bf) {
      const u16* wq = (const u16*)Wq + ((long)h * 64 + e) * 64;
      const u16* wk = (const u16*)Wk + ((long)h * 64 + col) * 64;
      for (int a = 0; a < 64; ++a) acc += bf2f(wq[a]) * bf2f(wk[a]);
    } else {
      const float* wq = (const float*)Wq + ((long)h * 64 + e) * 64;
      const float* wk = (const float*)Wk + ((long)h * 64 + col) * 64;
      for (int a = 0; a < 64; ++a) acc += wq[a] * wk[a];
    }
    u16 hi = f2bf(acc);
    ws[idx] = hi;                                // MH
    ws[idx + 16384] = f2bf(acc - bf2f(hi));      // ML
  } else {
    const void* src;
    long off;
    if (s == 1) { src = Wv;   off = ((long)h * 64 + e) * 64 + col; }
    else        { src = Wres; off = (long)e * 256 + h * 64 + col; }
    float v = bf ? bf2f(((const u16*)src)[off]) : ((const float*)src)[off];
    ws[idx + 16384] = f2bf(v);  // s=1 -> [32768,49152) VH ; s=2 -> [49152,65536) ResH
  }
}

// R11: ONE WAVE = ONE (b,h). 4 independent waves per block (h = wave id), ONE
// barrier total (X staging). No LDS tiles: T and V C-frags stay packed in
// registers and are redistributed into MFMA operand fragments with the same
// in-wave shuffle pattern proven bit-exact for P in R7. Rationale: ten rounds
// of phase-coupled 4-wave blocks all land 224-254us regardless of pipe-level
// changes -> the barrier coupling (wait-for-slowest, idle phase-2 wave) is the
// floor, not any pipe. Every arithmetic value here is bit-identical to R7.
//   per wave: V = X.Wv (12 C-tiles) -> redist -> vb[4] operand frags
//             per mt (unrolled): T^T = M^T.X^T (4 C-tiles) -> redist -> thf/tlf
//                                S^T = X.T^T ; in-register softmax ; P -> pf
//                                O^T = V^T.P^T + Wres^T.X^T ; relu ; store
// All register arrays statically indexed (full unrolls) -> no scratch.
// amdgpu_waves_per_eu(3,4): R10-proven lever against the 64-VGPR clamp.
template <bool USEWS>
__attribute__((amdgpu_waves_per_eu(3, 4)))
__global__ __launch_bounds__(256) void autoint_attn(
    const void* __restrict__ Xv, const void* __restrict__ Wq,
    const void* __restrict__ Wk, const void* __restrict__ Wv,
    const void* __restrict__ Wres, const u16* __restrict__ wp,
    void* __restrict__ outv) {
  __shared__ __align__(16) u16 smem[6144];  // 12288 B: X staging only
  const int tid = threadIdx.x;
  const int b = blockIdx.x;                 // 4096 blocks, one batch each
  const int w = tid >> 6, lane = tid & 63;
  const int q = lane >> 4, r = lane & 15;
  const int h = w;                          // wave = head
  const bool bf = detect_bf16(Wq);

  u16* XH = smem;            // [3 mt][2 kc][64 lane][8]  (valid whole kernel)
  u16* XL = smem + 3072;

  const u16* PMH = wp;
  const u16* PML = wp + 16384;
  const u16* PVH = wp + 32768;
  const u16* PRH = wp + 49152;

  // ---- stage X once per block (256 threads share the fp32->split VALU) ----
  for (int c = tid; c < 384; c += 256) {
    short8 hi8 = {0, 0, 0, 0, 0, 0, 0, 0}, lo8 = {0, 0, 0, 0, 0, 0, 0, 0};
    int f, ec;
    if (c < 320) {
      f = c >> 3; ec = c & 7;
      if (bf) {
        hi8 = *(const short8*)((const u16*)Xv + ((size_t)b * F_ + f) * E_ + ec * 8);
      } else {
        const float* xp = (const float*)Xv + ((size_t)b * F_ + f) * E_ + ec * 8;
        float4 p0 = *(const float4*)xp;
        float4 p1 = *(const float4*)(xp + 4);
        float vals[8] = {p0.x, p0.y, p0.z, p0.w, p1.x, p1.y, p1.z, p1.w};
#pragma unroll
        for (int j = 0; j < 8; ++j) {
          u16 hh = f2bf(vals[j]);
          hi8[j] = (short)hh;
          lo8[j] = (short)f2bf(vals[j] - bf2f(hh));
        }
      }
    } else {
      f = 40 + ((c - 320) >> 3); ec = c & 7;
    }
    int mt = f >> 4, rr = f & 15, kc = ec >> 2, qq = ec & 3;
    int base = ((mt * 2 + kc) * 64 + qq * 16 + rr) * 8;
    *(short8*)(XH + base) = hi8;
    *(short8*)(XL + base) = lo8;
  }
  __syncthreads();  // the ONLY barrier

  bf16x8 xh[3][2], xl[3][2];
#pragma unroll
  for (int mt = 0; mt < 3; ++mt)
#pragma unroll
    for (int kc = 0; kc < 2; ++kc) {
      xh[mt][kc] = *(const bf16x8*)(XH + ((mt * 2 + kc) * 64 + lane) * 8);
      xl[mt][kc] = *(const bf16x8*)(XL + ((mt * 2 + kc) * 64 + lane) * 8);
    }

  const void* Wq_p = bf ? (const void*)((const u16*)Wq + h * 4096)
                        : (const void*)((const float*)Wq + h * 4096);
  const void* Wk_p = bf ? (const void*)((const u16*)Wk + h * 4096)
                        : (const void*)((const float*)Wk + h * 4096);
  const void* Wv_p = bf ? (const void*)((const u16*)Wv + h * 4096)
                        : (const void*)((const float*)Wv + h * 4096);

  // ---- V = X.Wv, all 12 C-tiles; redist into PV A-operand frags vb0/vb1 ----
  // C-tile (ft,at): lane holds V[f=ft*16+q*4+i][a=at*16+r], packed bf16 pairs.
  // vb0[at] elem j = V[f=q*8+j][a=at*16+r]; vb1: f=32+q*8+j (f>=48 zero).
  bf16x8 vb0[4], vb1[4];
#pragma unroll
  for (int at = 0; at < 4; ++at) {
    bf16x8 wvf[2];
    if constexpr (USEWS) {
#pragma unroll
      for (int kc = 0; kc < 2; ++kc)
        wvf[kc] = *(const bf16x8*)(PVH + ((h * 4 + at) * 2 + kc) * 512 + lane * 8);
    } else {
      bf16x8 d;
      for (int kc = 0; kc < 2; ++kc) gather2(Wv_p, bf, 64, at * 16 + r, kc, q, wvf[kc], d);
    }
    u32 vpk[3][2];
#pragma unroll
    for (int ft = 0; ft < 3; ++ft) {
      floatx4 av = {0.f, 0.f, 0.f, 0.f};
      av = mfma16(xh[ft][0], wvf[0], av);
      av = mfma16(xh[ft][1], wvf[1], av);
      vpk[ft][0] = pkw(av[0], av[1]);
      vpk[ft][1] = pkw(av[2], av[3]);
    }
    vb0[at] = redist(vpk[0][0], vpk[0][1], vpk[1][0], vpk[1][1], q, r);
    vb1[at] = redist_half(vpk[2][0], vpk[2][1], q, r);  // f 40..47 are 0 (X pad)
  }

  // ---- per row-tile mt: T, S, softmax, P, PV+res, store (no cross-wave dep) ----
#pragma unroll
  for (int mt = 0; mt < 3; ++mt) {
    // T^T = M^T.X^T, tiles (mt, nt=0..3): lane holds T[f=mt*16+r][a=nt*16+q*4+i]
    u32 tpkh[4][2], tpkl[4][2];
#pragma unroll
    for (int nt = 0; nt < 4; ++nt) {
      bf16x8 mh[2], ml[2];
      if constexpr (USEWS) {
#pragma unroll
        for (int kc = 0; kc < 2; ++kc) {
          mh[kc] = *(const bf16x8*)(PMH + ((h * 4 + nt) * 2 + kc) * 512 + lane * 8);
          ml[kc] = *(const bf16x8*)(PML + ((h * 4 + nt) * 2 + kc) * 512 + lane * 8);
        }
      } else {
        for (int kc = 0; kc < 2; ++kc)
          gatherM2(Wq_p, Wk_p, bf, kc, q, nt * 16 + r, mh[kc], ml[kc]);
      }
      floatx4 at_ = {0.f, 0.f, 0.f, 0.f};
#pragma unroll
      for (int kc = 0; kc < 2; ++kc) {
        at_ = mfma16(mh[kc], xh[mt][kc], at_);   // Mh^T . Xh^T
        at_ = mfma16(ml[kc], xh[mt][kc], at_);   // Ml^T . Xh^T
        at_ = mfma16(mh[kc], xl[mt][kc], at_);   // Mh^T . Xl^T
      }
      u16 h0 = f2bf(at_[0]), h1 = f2bf(at_[1]), h2 = f2bf(at_[2]), h3 = f2bf(at_[3]);
      tpkh[nt][0] = (u32)h0 | ((u32)h1 << 16);
      tpkh[nt][1] = (u32)h2 | ((u32)h3 << 16);
      tpkl[nt][0] = (u32)f2bf(at_[0] - bf2f(h0)) | ((u32)f2bf(at_[1] - bf2f(h1)) << 16);
      tpkl[nt][1] = (u32)f2bf(at_[2] - bf2f(h2)) | ((u32)f2bf(at_[3] - bf2f(h3)) << 16);
    }
    // redist into S B-operand: thf[kc] elem j = T[f=mt*16+r][a=kc*32+q*8+j]
    bf16x8 thf[2], tlf[2];
    thf[0] = redist(tpkh[0][0], tpkh[0][1], tpkh[1][0], tpkh[1][1], q, r);
    thf[1] = redist(tpkh[2][0], tpkh[2][1], tpkh[3][0], tpkh[3][1], q, r);
    tlf[0] = redist(tpkl[0][0], tpkl[0][1], tpkl[1][0], tpkl[1][1], q, r);
    tlf[1] = redist(tpkl[2][0], tpkl[2][1], tpkl[3][0], tpkl[3][1], q, r);

    // S^T tiles: lane holds S[f=mt*16+r][g=gt*16+q*4+i]
    floatx4 sg[3];
#pragma unroll
    for (int gt = 0; gt < 3; ++gt) {
      floatx4 s = {0.f, 0.f, 0.f, 0.f};
#pragma unroll
      for (int kc = 0; kc < 2; ++kc) {
        s = mfma16(xh[gt][kc], thf[kc], s);   // Xh . Th^T
        s = mfma16(xl[gt][kc], thf[kc], s);   // Xl . Th^T
        s = mfma16(xh[gt][kc], tlf[kc], s);   // Xh . Tl^T
      }
      sg[gt] = s;
    }
    // in-register softmax over g; gt=2 has g=32+q*4+i, valid iff q<2
    const bool ok2 = (q < 2);
    float m = fmaxf(fmaxf(sg[0][0], sg[0][1]), fmaxf(sg[0][2], sg[0][3]));
    m = fmaxf(m, fmaxf(fmaxf(sg[1][0], sg[1][1]), fmaxf(sg[1][2], sg[1][3])));
    if (ok2)
      m = fmaxf(m, fmaxf(fmaxf(sg[2][0], sg[2][1]), fmaxf(sg[2][2], sg[2][3])));
    m = fmaxf(m, __shfl_xor(m, 16, 64));
    m = fmaxf(m, __shfl_xor(m, 32, 64));
    float p0[4], p1[4], p2[4], sum = 0.f;
#pragma unroll
    for (int i = 0; i < 4; ++i) {
      p0[i] = __expf(sg[0][i] - m);
      p1[i] = __expf(sg[1][i] - m);
      p2[i] = ok2 ? __expf(sg[2][i] - m) : 0.f;
      sum += p0[i] + p1[i] + p2[i];
    }
    sum += __shfl_xor(sum, 16, 64);
    sum += __shfl_xor(sum, 32, 64);
    float inv = 1.f / sum;

    // Wres frags for this mt (L2-hot; issue before P shuffles to hide latency)
    bf16x8 wr0[4], wr1[4];
    if constexpr (USEWS) {
#pragma unroll
      for (int nt = 0; nt < 4; ++nt) {
        wr0[nt] = *(const bf16x8*)(PRH + ((h * 4 + nt) * 2 + 0) * 512 + lane * 8);
        wr1[nt] = *(const bf16x8*)(PRH + ((h * 4 + nt) * 2 + 1) * 512 + lane * 8);
      }
    } else {
      for (int nt = 0; nt < 4; ++nt) {
        bf16x8 d;
        gather2(Wres, bf, 256, h * 64 + nt * 16 + r, 0, q, wr0[nt], d);
        gather2(Wres, bf, 256, h * 64 + nt * 16 + r, 1, q, wr1[nt], d);
      }
    }

    // P in registers (R7, bit-exact): pack normalized bf16 pairs, redist to
    // the PV B-operand. pf1 upper half zero (g 48..63).
    u32 A0 = pkw(p0[0] * inv, p0[1] * inv);
    u32 A1 = pkw(p0[2] * inv, p0[3] * inv);
    u32 B0 = pkw(p1[0] * inv, p1[1] * inv);
    u32 B1 = pkw(p1[2] * inv, p1[3] * inv);
    u32 C0 = pkw(p2[0] * inv, p2[1] * inv);   // zeros where ok2 false
    u32 C1 = pkw(p2[2] * inv, p2[3] * inv);
    bf16x8 pf0 = redist(A0, A1, B0, B1, q, r);        // g 0..31
    bf16x8 pf1 = redist_half(C0, C1, q, r);           // g 32..47, 48..63 = 0

    // O^T = V^T.P^T + Wres^T.X^T, relu, packed store
#pragma unroll
    for (int nt = 0; nt < 4; ++nt) {
      floatx4 acc = {0.f, 0.f, 0.f, 0.f};
      acc = mfma16(wr0[nt], xh[mt][0], acc);
      acc = mfma16(wr1[nt], xh[mt][1], acc);
      acc = mfma16(vb0[nt], pf0, acc);
      acc = mfma16(vb1[nt], pf1, acc);
      // lane holds O[f = mt*16+r][c = h*64 + nt*16 + q*4+i], i consecutive
      int f = mt * 16 + r;
      if (f < F_) {
        size_t o = ((size_t)b * F_ + f) * C_ + h * 64 + nt * 16 + q * 4;
        if (bf) {
          short4v ov;
#pragma unroll
          for (int i = 0; i < 4; ++i) ov[i] = (short)f2bf(fmaxf(acc[i], 0.f));
          *(short4v*)((u16*)outv + o) = ov;
        } else {
          floatx4 ov;
#pragma unroll
          for (int i = 0; i < 4; ++i) ov[i] = fmaxf(acc[i], 0.f);
          *(floatx4*)((float*)outv + o) = ov;
        }
      }
    }
  }
}

extern "C" void kernel_launch(void* const* d_in, const int* in_sizes, int n_in,
                              void* d_out, int out_size, void* d_ws, size_t ws_size,
                              hipStream_t stream) {
  (void)in_sizes; (void)n_in; (void)out_size;
  const void* X    = d_in[0];
  const void* Wq   = d_in[1];
  const void* Wk   = d_in[2];
  const void* Wv   = d_in[3];
  const void* Wres = d_in[4];

  bool usews = (d_ws != nullptr) && (ws_size >= 131072);
  if (usews) {
    pack_w<<<192, 256, 0, stream>>>(Wq, Wk, Wv, Wres, (u16*)d_ws);
    autoint_attn<true><<<B_, 256, 0, stream>>>(X, Wq, Wk, Wv, Wres,
                                               (const u16*)d_ws, d_out);
  } else {
    autoint_attn<false><<<B_, 256, 0, stream>>>(X, Wq, Wk, Wv, Wres,
                                                nullptr, d_out);
  }
}